// Round 2
// baseline (468.000 us; speedup 1.0000x reference)
//
#include <hip/hip_runtime.h>
#include <hip/hip_bf16.h>
#include <stdint.h>

#define VOCAB 32000
#define HID   256
#define BATCH 16
#define SEQT  256
#define ROWS  (BATCH*SEQT)   // 4096

typedef __attribute__((ext_vector_type(8))) short bf16x8_t;
typedef __attribute__((ext_vector_type(4))) float f32x4_t;

__device__ __forceinline__ short f2bs(float x) {
    __hip_bfloat16 h = __float2bfloat16(x);
    return *reinterpret_cast<short*>(&h);
}
__device__ __forceinline__ bf16x8_t cvt8(float4 a, float4 b) {
    union { short s[8]; bf16x8_t v; } u;
    u.s[0] = f2bs(a.x); u.s[1] = f2bs(a.y); u.s[2] = f2bs(a.z); u.s[3] = f2bs(a.w);
    u.s[4] = f2bs(b.x); u.s[5] = f2bs(b.y); u.s[6] = f2bs(b.z); u.s[7] = f2bs(b.w);
    return u.v;
}
// workgroup barrier draining ONLY lgkmcnt; vmem stays in flight
__device__ __forceinline__ void barrier_lds() {
    asm volatile("s_waitcnt lgkmcnt(0)\n\ts_barrier" ::: "memory");
}
// tanh via exp2: tanh(x) = 1 - 2/(2^(2*log2(e)*x)+1); saturates naturally.
__device__ __forceinline__ float tanh_exp(float x) {
    float e = __builtin_amdgcn_exp2f(x * 2.885390081777927f);
    return fmaf(-2.f, __builtin_amdgcn_rcpf(e + 1.f), 1.f);
}
// pack two f32 -> one dword of 2 bf16 (RNE), lo = first operand
__device__ __forceinline__ uint32_t pk_bf16(float lo, float hi) {
    uint32_t r;
    asm("v_cvt_pk_bf16_f32 %0, %1, %2" : "=v"(r) : "v"(lo), "v"(hi));
    return r;
}

// ===========================================================================
// Swizzled fragment layout (shared by A=hs and B=Wfcb):
//   element (row, k) -> swz[ (row>>4)*4096 + (k>>5)*512 + ((k>>3)&3)*128
//                            + (row&15)*8 + (k&7) ]
// i.e. [16-row tile][ki 0..7][lane l=lh*16+lr][j 0..7]; a wave's MFMA
// fragment (one 16-tile, one ki) is 1 KB CONTIGUOUS -> coalesced 16B/lane
// global loads straight into mfma operand registers. No LDS staging.
// ===========================================================================

// ---------------------------------------------------------------------------
// K1: xp[t][b][h] = Wih[inputs[b][t]][h]+bih[h]+bhh[h]; zeroes S; converts
// Wfc fp32 -> bf16 into SWIZZLED Wfcb. 4096 blocks x 256.
// ---------------------------------------------------------------------------
__global__ __launch_bounds__(256) void xproj_kernel(
    const int* __restrict__ inputs,
    const float* __restrict__ Wih,
    const float* __restrict__ bih,
    const float* __restrict__ bhh,
    const float* __restrict__ Wfc,
    float* __restrict__ xp,
    float* __restrict__ S,
    __hip_bfloat16* __restrict__ Wfcb,
    int do_cvt)
{
    int idx = blockIdx.x * 256 + threadIdx.x;  // (t*16+b)*256 + h
    int h  = idx & 255;
    int tb = idx >> 8;
    int b  = tb & 15;
    int t  = tb >> 4;
    int id = inputs[b * SEQT + t];
    xp[idx] = Wih[(size_t)id * HID + h] + bih[h] + bhh[h];
    if (idx < ROWS) S[idx] = 0.0f;
    if (do_cvt && idx < (VOCAB * HID / 8)) {
        const float4* p = (const float4*)(Wfc + (size_t)idx * 8);
        int n  = idx >> 5;          // row (vocab)
        int c  = idx & 31;          // k-chunk: k0 = c*8
        int ki = c >> 2;            // (c*8)>>5
        int lh = c & 3;             // ((c*8)>>3)&3
        size_t dst = (size_t)(n >> 4) * 4096 + ki * 512 + lh * 128 + (n & 15) * 8;
        *(bf16x8_t*)((short*)Wfcb + dst) = cvt8(p[0], p[1]);
    }
}

// ---------------------------------------------------------------------------
// K2: RNN recurrence. One block, 512 threads (8 waves), M=16, N=K=256.
// Unchanged structure; hs store now writes the SWIZZLED fragment layout
// (address-arithmetic-only change: still one b128 store/thread/step).
// ---------------------------------------------------------------------------
__global__ __launch_bounds__(512, 1) void rnn_kernel(
    const float* __restrict__ xp,          // [T][B][H] fp32 (biases folded)
    const float* __restrict__ Whh,
    __hip_bfloat16* __restrict__ hs)       // swizzled A for fc
{
    __shared__ short hbuf[2][16][264];     // +8 pad
    const int tid = threadIdx.x;
    const int l = tid & 63, w = tid >> 6;
    const int lr = l & 15, lh = l >> 4;
    const int cm = tid >> 5;               // copy: row (=b) 0..15
    const int cc = (tid & 31) * 8;         // copy: col (x8 shorts)
    const int n0 = w * 32 + lr * 2;        // this lane's even column
    // swizzled dest offset within a 16-row tile (tile index = t)
    const int cpoff = ((cc >> 5) * 512) + (((cc >> 3) & 3) * 128) + cm * 8;

    // B fragments: tile nt covers logical col n = n0+nt
    bf16x8_t bfrag[2][8];
#pragma unroll
    for (int nt = 0; nt < 2; nt++) {
#pragma unroll
        for (int ki = 0; ki < 8; ki++) {
            const float4* p = (const float4*)(Whh + (size_t)(n0 + nt) * HID + ki * 32 + lh * 8);
            bfrag[nt][ki] = cvt8(p[0], p[1]);
        }
    }
    for (int i = tid; i < 16 * 264; i += 512) ((short*)hbuf[0])[i] = 0;
    __syncthreads();

    float2 xva[4], xvb[4];
#pragma unroll
    for (int r = 0; r < 4; r++)
        xva[r] = *(const float2*)(xp + (lh * 4 + r) * HID + n0);

    auto step = [&](int SRC, int DST, float2* xv, float2* xn, int t) {
        // pipelined copy of h_{t-1} (in hbuf[SRC]) to swizzled hs
        if (t > 0) {
            bf16x8_t hv = *(const bf16x8_t*)(&hbuf[SRC][cm][cc]);
            *(bf16x8_t*)((short*)hs + (size_t)(t - 1) * 4096 + cpoff) = hv;
        }
        bf16x8_t afr[8];
#pragma unroll
        for (int ki = 0; ki < 8; ki++)
            afr[ki] = *(const bf16x8_t*)(&hbuf[SRC][lr][ki * 32 + lh * 8]);

        f32x4_t a0a = {xv[0].x, xv[1].x, xv[2].x, xv[3].x};
        f32x4_t a1a = {xv[0].y, xv[1].y, xv[2].y, xv[3].y};
        f32x4_t a0b = {0.f, 0.f, 0.f, 0.f};
        f32x4_t a1b = {0.f, 0.f, 0.f, 0.f};
#pragma unroll
        for (int ki = 0; ki < 4; ki++) {
            a0a = __builtin_amdgcn_mfma_f32_16x16x32_bf16(afr[ki],     bfrag[0][ki],     a0a, 0, 0, 0);
            a0b = __builtin_amdgcn_mfma_f32_16x16x32_bf16(afr[ki + 4], bfrag[0][ki + 4], a0b, 0, 0, 0);
            a1a = __builtin_amdgcn_mfma_f32_16x16x32_bf16(afr[ki],     bfrag[1][ki],     a1a, 0, 0, 0);
            a1b = __builtin_amdgcn_mfma_f32_16x16x32_bf16(afr[ki + 4], bfrag[1][ki + 4], a1b, 0, 0, 0);
        }

        if (t + 1 < SEQT) {
            const float* xb = xp + (size_t)(t + 1) * (BATCH * HID);
#pragma unroll
            for (int r = 0; r < 4; r++)
                xn[r] = *(const float2*)(xb + (lh * 4 + r) * HID + n0);
        }

#pragma unroll
        for (int r = 0; r < 4; r++) {
            float v0 = a0a[r] + a0b[r];
            float v1 = a1a[r] + a1b[r];
            uint32_t pk = pk_bf16(tanh_exp(v0), tanh_exp(v1));
            *(uint32_t*)(&hbuf[DST][lh * 4 + r][n0]) = pk;
        }
        barrier_lds();
    };

    for (int t = 0; t < SEQT; t += 2) {
        step(0, 1, xva, xvb, t);
        step(1, 0, xvb, xva, t + 1);
    }
    bf16x8_t hv = *(const bf16x8_t*)(&hbuf[0][cm][cc]);
    *(bf16x8_t*)((short*)hs + (size_t)(SEQT - 1) * 4096 + cpoff) = hv;
}

// ---------------------------------------------------------------------------
// K3: fused FC GEMM + exp-rowsum + target-logit extraction. NO LDS staging:
// A and B fragments loaded directly global->VGPR from swizzled layouts
// (1 KB contiguous per wave-load). Zero main-loop barriers; register
// double-buffered over ki. XCD-swizzled grid keeps each n-panel's B
// (~2 MB) in one XCD's L2; A (2 MB) fits every L2.
// BF16B=false fallback: per-lane strided fp32 loads from raw Wfc.
// ---------------------------------------------------------------------------
template <bool BF16B>
__global__ __launch_bounds__(256) void fc_kernel(
    const __hip_bfloat16* __restrict__ hsz,   // A swizzled [256][8][64][8]
    const void* __restrict__ WfcP,            // BF16B: swizzled bf16; else raw fp32
    const float* __restrict__ bfc,
    const int* __restrict__ targets,
    float* __restrict__ S,
    float* __restrict__ TL)
{
    __shared__ int tgt[128];

    const int bid = blockIdx.x;
    const int xcd = bid & 7;
    const int j   = bid >> 3;
    const int m_id = j & 31;
    const int n_id = (j >> 5) * 8 + xcd;
    if (n_id >= VOCAB / 128) return;
    const int m0 = m_id * 128, n0 = n_id * 128;

    const int tid = threadIdx.x;
    const int l = tid & 63, w = tid >> 6;
    const int lr = l & 15, lh = l >> 4;
    const int wm = (w >> 1) * 64, wn = (w & 1) * 64;

    if (tid < 128) {
        int r = m0 + tid;                        // r = t*16+b
        tgt[tid] = targets[((r & 15) << 8) | (r >> 4)];
    }

    // fragment base pointers (offsets in shorts); mt/nt stride 4096, ki stride 512
    const short* Ab = (const short*)hsz +
        ((size_t)(m_id * 8 + (wm >> 4)) * 8) * 512 + l * 8;
    const short* Bb = (const short*)WfcP +
        ((size_t)(n_id * 8 + (wn >> 4)) * 8) * 512 + l * 8;
    const float* Bf = (const float*)WfcP;

    f32x4_t acc[4][4];
    const f32x4_t z = {0.f, 0.f, 0.f, 0.f};
#pragma unroll
    for (int i = 0; i < 4; i++)
#pragma unroll
        for (int jj = 0; jj < 4; jj++) acc[i][jj] = z;

    bf16x8_t a[2][4], b[2][4];
    auto loadA = [&](int buf, int ki) {
#pragma unroll
        for (int mt = 0; mt < 4; mt++)
            a[buf][mt] = *(const bf16x8_t*)(Ab + mt * 4096 + ki * 512);
    };
    auto loadB = [&](int buf, int ki) {
#pragma unroll
        for (int nt = 0; nt < 4; nt++) {
            if (BF16B) {
                b[buf][nt] = *(const bf16x8_t*)(Bb + nt * 4096 + ki * 512);
            } else {
                int n = n0 + wn + nt * 16 + lr;
                const float4* p = (const float4*)(Bf + (size_t)n * HID + ki * 32 + lh * 8);
                b[buf][nt] = cvt8(p[0], p[1]);
            }
        }
    };

    loadA(0, 0); loadB(0, 0);
#pragma unroll
    for (int ki = 0; ki < 8; ki++) {
        const int cur = ki & 1;
        if (ki < 7) { loadA(cur ^ 1, ki + 1); loadB(cur ^ 1, ki + 1); }
#pragma unroll
        for (int mt = 0; mt < 4; mt++)
#pragma unroll
            for (int nt = 0; nt < 4; nt++)
                acc[mt][nt] = __builtin_amdgcn_mfma_f32_16x16x32_bf16(
                    a[cur][mt], b[cur][nt], acc[mt][nt], 0, 0, 0);
    }
    __syncthreads();   // tgt visibility (only barrier in the kernel)

    // epilogue: bias + exp + rowsum; extract target logits inline
    int tg[16];
#pragma unroll
    for (int i = 0; i < 16; i++)
        tg[i] = tgt[wm + (i >> 2) * 16 + lh * 4 + (i & 3)];

    float rsum[16];
#pragma unroll
    for (int i = 0; i < 16; i++) rsum[i] = 0.f;
#pragma unroll
    for (int nt = 0; nt < 4; nt++) {
        int n = n0 + wn + nt * 16 + lr;
        float bias = bfc[n];
#pragma unroll
        for (int mt = 0; mt < 4; mt++)
#pragma unroll
            for (int r = 0; r < 4; r++) {
                float v = acc[mt][nt][r] + bias;
                rsum[mt * 4 + r] += __expf(v);
                if (tg[mt * 4 + r] == n)
                    TL[m0 + wm + mt * 16 + lh * 4 + r] = v;
            }
    }
#pragma unroll
    for (int m = 1; m < 16; m <<= 1)
#pragma unroll
        for (int i = 0; i < 16; i++) rsum[i] += __shfl_xor(rsum[i], m, 64);
    if (lr == 0) {
#pragma unroll
        for (int i = 0; i < 16; i++) {
            int r = m0 + wm + (i >> 2) * 16 + lh * 4 + (i & 3);
            atomicAdd(&S[r], rsum[i]);
        }
    }
}

// ---------------------------------------------------------------------------
// K4: loss = mean_r( log(S[r]) - TL[r] )
// ---------------------------------------------------------------------------
__global__ __launch_bounds__(256) void loss_kernel(
    const float* __restrict__ S,
    const float* __restrict__ TL,
    float* __restrict__ out)
{
    int tid = threadIdx.x;
    float p = 0.f;
    for (int i = tid; i < ROWS; i += 256) p += __logf(S[i]) - TL[i];
#pragma unroll
    for (int m = 1; m < 64; m <<= 1) p += __shfl_xor(p, m, 64);
    __shared__ float red[4];
    if ((tid & 63) == 0) red[tid >> 6] = p;
    __syncthreads();
    if (tid == 0)
        out[0] = (red[0] + red[1] + red[2] + red[3]) / (float)ROWS;
}

extern "C" void kernel_launch(void* const* d_in, const int* in_sizes, int n_in,
                              void* d_out, int out_size, void* d_ws, size_t ws_size,
                              hipStream_t stream)
{
    (void)in_sizes; (void)n_in; (void)out_size;
    const int*   inputs  = (const int*)d_in[0];
    const int*   targets = (const int*)d_in[1];
    const float* Wih = (const float*)d_in[2];
    const float* bih = (const float*)d_in[3];
    const float* Whh = (const float*)d_in[4];
    const float* bhh = (const float*)d_in[5];
    const float* Wfc = (const float*)d_in[6];
    const float* bfc = (const float*)d_in[7];

    float* S  = (float*)d_ws;                           // 4096 f32
    float* TL = S + ROWS;                               // 4096 f32
    float* xp = TL + ROWS;                              // [T][B][H] fp32, 4 MB
    __hip_bfloat16* hs = (__hip_bfloat16*)(xp + (size_t)SEQT * BATCH * HID); // 2 MB (swizzled)
    __hip_bfloat16* Wfcb = hs + (size_t)ROWS * HID;     // 32000x256 bf16 swizzled, 16 MB

    const size_t need = (size_t)(2 * ROWS) * 4 + (size_t)ROWS * HID * 4
                      + (size_t)ROWS * HID * 2 + (size_t)VOCAB * HID * 2;
    const int use_bf16b = (ws_size >= need) ? 1 : 0;

    xproj_kernel<<<(SEQT * BATCH * HID) / 256, 256, 0, stream>>>(
        inputs, Wih, bih, bhh, Wfc, xp, S, Wfcb, use_bf16b);
    rnn_kernel<<<1, 512, 0, stream>>>(xp, Whh, hs);
    if (use_bf16b)
        fc_kernel<true><<<8192, 256, 0, stream>>>(hs, (const void*)Wfcb, bfc, targets, S, TL);
    else
        fc_kernel<false><<<8192, 256, 0, stream>>>(hs, (const void*)Wfc, bfc, targets, S, TL);
    loss_kernel<<<1, 256, 0, stream>>>(S, TL, (float*)d_out);
}